// Round 4
// baseline (1126.605 us; speedup 1.0000x reference)
//
#include <hip/hip_runtime.h>

#define B_ 4
#define H_ 256
#define W_ 256
#define Z_ 64
#define NB_ (H_*W_*Z_)      /* 4194304 */
#define N_  (B_*NB_)        /* 16777216 */
#define ITER_ 8
#define EPS_ 1e-6f
#define SLOTS_ 64
#define NTILE_ 8192

/* scal layout (floats) */
#define RHO_OFF   0
#define ETA_OFF   ((ITER_+1)*B_*SLOTS_)
#define LOSS_OFF  (ETA_OFF + ITER_*B_*SLOTS_)
#define MAXE_OFF  (LOSS_OFF + SLOTS_)
#define TICK_OFF  (MAXE_OFF + SLOTS_)
#define SCAL_FLOATS (TICK_OFF + 32)

struct F8 { float4 a, b; };

__device__ __forceinline__ float wsum(float v){
  v += __shfl_xor(v,32); v += __shfl_xor(v,16); v += __shfl_xor(v,8);
  v += __shfl_xor(v,4);  v += __shfl_xor(v,2);  v += __shfl_xor(v,1);
  return v;
}
__device__ __forceinline__ float wmaxr(float v){
  v = fmaxf(v,__shfl_xor(v,32)); v = fmaxf(v,__shfl_xor(v,16));
  v = fmaxf(v,__shfl_xor(v,8));  v = fmaxf(v,__shfl_xor(v,4));
  v = fmaxf(v,__shfl_xor(v,2));  v = fmaxf(v,__shfl_xor(v,1));
  return v;
}
__device__ __forceinline__ float read_sum(const float* s){
  return wsum(s[threadIdx.x & 63]);
}
__device__ __forceinline__ void block_atomic_sum(float v, float* dst, float* lds){
  v = wsum(v);
  int wid = threadIdx.x >> 6, lane = threadIdx.x & 63;
  if (lane == 0) lds[wid] = v;
  __syncthreads();
  if (threadIdx.x == 0) atomicAdd(dst, lds[0]+lds[1]+lds[2]+lds[3]);
}

__device__ __forceinline__ float4 ld4(const float* p){ return *(const float4*)p; }

__device__ __forceinline__ void sub8(F8& s, const F8& n){
  s.a.x-=n.a.x; s.a.y-=n.a.y; s.a.z-=n.a.z; s.a.w-=n.a.w;
  s.b.x-=n.b.x; s.b.y-=n.b.y; s.b.z-=n.b.z; s.b.w-=n.b.w;
}

/* z-part of stencil: zl/zr via wave shuffle (neighbor lane's center values).
   lane L has zc = L&7; zc>0 -> zl = lane L-1's c.b.w; zc<7 -> zr = lane L+1's c.a.x */
__device__ __forceinline__ void zcore(const F8& c, int zc, F8& st){
  float zl = __shfl_up(c.b.w, 1);
  float zr = __shfl_down(c.a.x, 1);
  zl = (zc > 0) ? zl : 0.f;
  zr = (zc < 7) ? zr : 0.f;
  st.a.x = 6.f*c.a.x - zl    - c.a.y;
  st.a.y = 6.f*c.a.y - c.a.x - c.a.z;
  st.a.z = 6.f*c.a.z - c.a.y - c.a.w;
  st.a.w = 6.f*c.a.w - c.a.z - c.b.x;
  st.b.x = 6.f*c.b.x - c.a.w - c.b.y;
  st.b.y = 6.f*c.b.y - c.b.x - c.b.z;
  st.b.z = 6.f*c.b.z - c.b.y - c.b.w;
  st.b.w = 6.f*c.b.w - c.b.z - zr;
}

__device__ __forceinline__ void stencil1(const float* __restrict__ a, int base,
                                         int w, int h, int zc, F8& c, F8& st)
{
  c.a = ld4(a+base); c.b = ld4(a+base+4);
  zcore(c, zc, st);
  F8 t;
  if (w > 0)    { t.a = ld4(a+base-Z_);    t.b = ld4(a+base-Z_+4);    sub8(st,t); }
  if (w < W_-1) { t.a = ld4(a+base+Z_);    t.b = ld4(a+base+Z_+4);    sub8(st,t); }
  if (h > 0)    { t.a = ld4(a+base-W_*Z_); t.b = ld4(a+base-W_*Z_+4); sub8(st,t); }
  if (h < H_-1) { t.a = ld4(a+base+W_*Z_); t.b = ld4(a+base+W_*Z_+4); sub8(st,t); }
}

__device__ __forceinline__ F8 comb8(const float* r, const float* p, float beta, int idx){
  F8 o;
  float4 ra = ld4(r+idx), rb = ld4(r+idx+4);
  float4 pa = ld4(p+idx), pb = ld4(p+idx+4);
  o.a.x = ra.x + beta*pa.x; o.a.y = ra.y + beta*pa.y;
  o.a.z = ra.z + beta*pa.z; o.a.w = ra.w + beta*pa.w;
  o.b.x = rb.x + beta*pb.x; o.b.y = rb.y + beta*pb.y;
  o.b.z = rb.z + beta*pb.z; o.b.w = rb.w + beta*pb.w;
  return o;
}
__device__ __forceinline__ void stencil2(const float* __restrict__ r,
                                         const float* __restrict__ p, float beta,
                                         int base, int w, int h, int zc,
                                         F8& c, F8& st)
{
  c = comb8(r,p,beta,base);
  zcore(c, zc, st);
  if (w > 0)    sub8(st, comb8(r,p,beta,base-Z_));
  if (w < W_-1) sub8(st, comb8(r,p,beta,base+Z_));
  if (h > 0)    sub8(st, comb8(r,p,beta,base-W_*Z_));
  if (h < H_-1) sub8(st, comb8(r,p,beta,base+W_*Z_));
}

__device__ __forceinline__ float dot8(const F8& a, const F8& b){
  return a.a.x*b.a.x + a.a.y*b.a.y + a.a.z*b.a.z + a.a.w*b.a.w
       + a.b.x*b.b.x + a.b.y*b.b.y + a.b.z*b.b.z + a.b.w*b.b.w;
}

#define IDX_SETUP \
  const int zc = threadIdx.x & 7; \
  const int wl = threadIdx.x >> 3; \
  const int w  = blockIdx.x*32 + wl; \
  const int h  = blockIdx.y; \
  const int bb = blockIdx.z; \
  const int base = ((bb*H_ + h)*W_ + w)*Z_ + zc*8; \
  const int flat = (blockIdx.z*gridDim.y + blockIdx.y)*gridDim.x + blockIdx.x; \
  const int slot = flat & (SLOTS_-1);

#define XI(k) ((((k) >> 3)*9) + ((k) & 7))   /* padded LDS index, stride 9 */

/* r = b - A x ; rho0 = <r,r> per batch */
__global__ __launch_bounds__(256) void k_init(const float* __restrict__ x,
                                              const float* __restrict__ b,
                                              float* __restrict__ r,
                                              float* scal)
{
  __shared__ float lds[4];
  IDX_SETUP
  F8 c, st;
  stencil1(x, base, w, h, zc, c, st);
  float4 b0 = ld4(b+base);
  float4 b1 = ld4(b+base+4);
  F8 rv;
  rv.a = make_float4(b0.x-st.a.x, b0.y-st.a.y, b0.z-st.a.z, b0.w-st.a.w);
  rv.b = make_float4(b1.x-st.b.x, b1.y-st.b.y, b1.z-st.b.z, b1.w-st.b.w);
  *(float4*)(r+base)   = rv.a;
  *(float4*)(r+base+4) = rv.b;
  block_atomic_sum(dot8(rv,rv), scal + RHO_OFF + (0*B_+bb)*SLOTS_ + slot, lds);
}

/* it==0: eta0 = <r, A r>; optional p0 = r copy (fallback path only) */
__global__ __launch_bounds__(256) void k_a0(const float* __restrict__ r,
                                            float* __restrict__ pnew,
                                            float* scal)
{
  __shared__ float lds[4];
  IDX_SETUP
  F8 c, st;
  stencil1(r, base, w, h, zc, c, st);
  if (pnew) { *(float4*)(pnew+base) = c.a; *(float4*)(pnew+base+4) = c.b; }
  block_atomic_sum(dot8(c,st), scal + ETA_OFF + (0*B_+bb)*SLOTS_ + slot, lds);
}

/* it>=1: p_new = r + beta*p_old ; eta = <p_new, A p_new> per batch */
__global__ __launch_bounds__(256) void k_a(const float* __restrict__ r,
                                           const float* __restrict__ pold,
                                           float* __restrict__ pnew,
                                           float* scal, int it)
{
  __shared__ float lds[4];
  IDX_SETUP
  float num = read_sum(scal + RHO_OFF + (it*B_+bb)*SLOTS_);
  float den = read_sum(scal + RHO_OFF + ((it-1)*B_+bb)*SLOTS_);
  float beta = num / (den + EPS_);
  F8 c, st;
  stencil2(r, pold, beta, base, w, h, zc, c, st);
  *(float4*)(pnew+base)   = c.a;
  *(float4*)(pnew+base+4) = c.b;
  block_atomic_sum(dot8(c,st), scal + ETA_OFF + (it*B_+bb)*SLOTS_ + slot, lds);
}

/* it<7: alpha; x += alpha p; r_out = r_in - alpha*A p; rho_next = <r,r>.
   r_in may alias p (it==0, p0==r0) and r_out may alias r_in (in-place). */
__global__ __launch_bounds__(256) void k_b(float* __restrict__ x,
                                           const float* r_in,
                                           float* r_out,
                                           const float* p,
                                           float* scal, int it)
{
  __shared__ float lds[4];
  IDX_SETUP
  float num = read_sum(scal + RHO_OFF + (it*B_+bb)*SLOTS_);
  float den = read_sum(scal + ETA_OFF + (it*B_+bb)*SLOTS_);
  float alpha = num / (den + EPS_);
  F8 c, st;
  stencil1(p, base, w, h, zc, c, st);
  float4 x0 = ld4(x+base), x1 = ld4(x+base+4);
  x0.x += alpha*c.a.x; x0.y += alpha*c.a.y; x0.z += alpha*c.a.z; x0.w += alpha*c.a.w;
  x1.x += alpha*c.b.x; x1.y += alpha*c.b.y; x1.z += alpha*c.b.z; x1.w += alpha*c.b.w;
  *(float4*)(x+base)   = x0;
  *(float4*)(x+base+4) = x1;
  float4 r0 = ld4(r_in+base), r1 = ld4(r_in+base+4);
  r0.x -= alpha*st.a.x; r0.y -= alpha*st.a.y; r0.z -= alpha*st.a.z; r0.w -= alpha*st.a.w;
  r1.x -= alpha*st.b.x; r1.y -= alpha*st.b.y; r1.z -= alpha*st.b.z; r1.w -= alpha*st.b.w;
  *(float4*)(r_out+base)   = r0;
  *(float4*)(r_out+base+4) = r1;
  float rho = r0.x*r0.x + r0.y*r0.y + r0.z*r0.z + r0.w*r0.w
            + r1.x*r1.x + r1.y*r1.y + r1.z*r1.z + r1.w*r1.w;
  block_atomic_sum(rho, scal + RHO_OFF + ((it+1)*B_+bb)*SLOTS_ + slot, lds);
}

/* it==7 fused with epilogue + final scalar fold (last-block ticket). */
__global__ __launch_bounds__(256) void k_b_fin(const float* __restrict__ x,
                                               const float* __restrict__ r,
                                               const float* __restrict__ p,
                                               const float* __restrict__ ref,
                                               float* __restrict__ out,
                                               float* scal, int it)
{
  __shared__ float xs[256*9];   /* padded stride-9 staging: no bank conflicts */
  __shared__ float lds[12];
  __shared__ unsigned is_last;
  IDX_SETUP
  const int t = threadIdx.x;
  float num = read_sum(scal + RHO_OFF + (it*B_+bb)*SLOTS_);
  float den = read_sum(scal + ETA_OFF + (it*B_+bb)*SLOTS_);
  float alpha = num / (den + EPS_);
  F8 c, st;
  stencil1(p, base, w, h, zc, c, st);
  float4 x0 = ld4(x+base), x1 = ld4(x+base+4);
  x0.x += alpha*c.a.x; x0.y += alpha*c.a.y; x0.z += alpha*c.a.z; x0.w += alpha*c.a.w;
  x1.x += alpha*c.b.x; x1.y += alpha*c.b.y; x1.z += alpha*c.b.z; x1.w += alpha*c.b.w;
  float4 r0 = ld4(r+base), r1 = ld4(r+base+4);
  r0.x -= alpha*st.a.x; r0.y -= alpha*st.a.y; r0.z -= alpha*st.a.z; r0.w -= alpha*st.a.w;
  r1.x -= alpha*st.b.x; r1.y -= alpha*st.b.y; r1.z -= alpha*st.b.z; r1.w -= alpha*st.b.w;
  float rho = r0.x*r0.x + r0.y*r0.y + r0.z*r0.z + r0.w*r0.w
            + r1.x*r1.x + r1.y*r1.y + r1.z*r1.z + r1.w*r1.w;

  xs[t*9+0] = x0.x; xs[t*9+1] = x0.y; xs[t*9+2] = x0.z; xs[t*9+3] = x0.w;
  xs[t*9+4] = x1.x; xs[t*9+5] = x1.y; xs[t*9+6] = x1.z; xs[t*9+7] = x1.w;

  float4 f0 = ld4(ref+base);
  float4 f1 = ld4(ref+base+4);
  float d0 = x0.x-f0.x, d1 = x0.y-f0.y, d2 = x0.z-f0.z, d3 = x0.w-f0.w;
  float d4 = x1.x-f1.x, d5 = x1.y-f1.y, d6 = x1.z-f1.z, d7 = x1.w-f1.w;
  float loss = d0*d0+d1*d1+d2*d2+d3*d3+d4*d4+d5*d5+d6*d6+d7*d7;
  float me = fmaxf(fmaxf(fmaxf(fabsf(d0),fabsf(d1)),fmaxf(fabsf(d2),fabsf(d3))),
                   fmaxf(fmaxf(fabsf(d4),fabsf(d5)),fmaxf(fabsf(d6),fabsf(d7))));

  float rs = wsum(rho), ls = wsum(loss), ms = wmaxr(me);
  int wid = t >> 6, lane = t & 63;
  if (lane == 0) { lds[wid] = rs; lds[4+wid] = ls; lds[8+wid] = ms; }
  __syncthreads();
  if (t == 0) {
    atomicAdd(scal + RHO_OFF + ((it+1)*B_+bb)*SLOTS_ + slot, lds[0]+lds[1]+lds[2]+lds[3]);
    atomicAdd(scal + LOSS_OFF + slot, lds[4]+lds[5]+lds[6]+lds[7]);
    float bm = fmaxf(fmaxf(lds[8],lds[9]), fmaxf(lds[10],lds[11]));
    atomicMax((unsigned int*)(scal + MAXE_OFF) + slot, __float_as_uint(bm));
    /* order the above device-scope atomics before the ticket */
    asm volatile("s_waitcnt vmcnt(0)" ::: "memory");
    unsigned old = __hip_atomic_fetch_add((unsigned*)(scal + TICK_OFF), 1u,
                                          __ATOMIC_RELAXED, __HIP_MEMORY_SCOPE_AGENT);
    is_last = (old == NTILE_-1) ? 1u : 0u;
  }

  /* aligned shifted stores: out span [1+S, 2048+S] */
  const int S = flat * 2048;
  #pragma unroll
  for (int c2 = 0; c2 < 2; ++c2) {
    int q = t + 256*c2;
    if (q < 511) {
      int k = 4*q + 3;
      float4 v = make_float4(xs[XI(k)], xs[XI(k+1)], xs[XI(k+2)], xs[XI(k+3)]);
      *(float4*)(out + S + 4 + 4*q) = v;
    } else if (q == 511) {
      out[S+1] = xs[XI(0)]; out[S+2] = xs[XI(1)]; out[S+3] = xs[XI(2)];
      out[S+2048] = xs[XI(2047)];
    }
  }

  __syncthreads();
  /* last block folds the final scalars (reads via agent-scope atomic loads) */
  if (is_last && t < 64) {
    float lossv = wsum(__hip_atomic_load(scal + LOSS_OFF + t,
                                         __ATOMIC_RELAXED, __HIP_MEMORY_SCOPE_AGENT));
    unsigned mu = __hip_atomic_load((unsigned*)scal + MAXE_OFF + t,
                                    __ATOMIC_RELAXED, __HIP_MEMORY_SCOPE_AGENT);
    float mev = wmaxr(__uint_as_float(mu));
    float rho_sum = 0.f;
    for (int b2 = 0; b2 < B_; ++b2)
      rho_sum += wsum(__hip_atomic_load(scal + RHO_OFF + (ITER_*B_+b2)*SLOTS_ + t,
                                        __ATOMIC_RELAXED, __HIP_MEMORY_SCOPE_AGENT));
    if (t == 0) {
      out[0]    = lossv / (float)N_;
      out[1+N_] = mev;
      out[2+N_] = rho_sum / (float)B_;
    }
  }
}

extern "C" void kernel_launch(void* const* d_in, const int* in_sizes, int n_in,
                              void* d_out, int out_size, void* d_ws, size_t ws_size,
                              hipStream_t stream) {
  float* x         = (float*)d_in[0];
  const float* bv  = (const float*)d_in[1];
  const float* ref = (const float*)d_in[2];
  float* out       = (float*)d_out;
  float* ws        = (float*)d_ws;

  dim3 grid(W_/32, H_, B_), blk(256);
  bool fast = ws_size >= ((size_t)3*N_ + SCAL_FLOATS) * sizeof(float);

  if (fast) {
    /* R0 = r0 (== p0), R1 = live r, P0/P1 = p ping-pong (P1 = out scratch) */
    float* R0 = ws;
    float* R1 = ws + N_;
    float* P0 = ws + 2*(size_t)N_;
    float* P1 = out;
    float* scal = ws + 3*(size_t)N_;
    (void)hipMemsetAsync(scal, 0, SCAL_FLOATS*sizeof(float), stream);

    k_init<<<grid, blk, 0, stream>>>(x, bv, R0, scal);
    k_a0  <<<grid, blk, 0, stream>>>(R0, nullptr, scal);          /* p0 == r0 */
    k_b   <<<grid, blk, 0, stream>>>(x, R0, R1, R0, scal, 0);     /* r1 -> R1 */
    float* pa = P0; float* pb = R0;
    for (int it = 1; it < ITER_; ++it) {
      k_a<<<grid, blk, 0, stream>>>(R1, pb, pa, scal, it);
      if (it < ITER_-1)
        k_b<<<grid, blk, 0, stream>>>(x, R1, R1, pa, scal, it);   /* in-place r */
      else
        k_b_fin<<<grid, blk, 0, stream>>>(x, R1, pa, ref, out, scal, it);
      pb = pa; pa = (pa == P0) ? P1 : P0;
    }
    /* parity: it=1..7 -> pa = P0,P1,P0,P1,P0,P1,P0 ; fin reads P0 (ws, not out) */
  } else {
    /* fallback: r in-place in ws0; p ping-pong ws1/out; it0 copies p0 to out */
    float* r    = ws;
    float* p0w  = ws + N_;
    float* scal = ws + 2*(size_t)N_;
    (void)hipMemsetAsync(scal, 0, SCAL_FLOATS*sizeof(float), stream);

    k_init<<<grid, blk, 0, stream>>>(x, bv, r, scal);
    k_a0  <<<grid, blk, 0, stream>>>(r, out, scal);               /* p0 -> out */
    k_b   <<<grid, blk, 0, stream>>>(x, r, r, out, scal, 0);
    float* pa = p0w; float* pb = out;
    for (int it = 1; it < ITER_; ++it) {
      k_a<<<grid, blk, 0, stream>>>(r, pb, pa, scal, it);
      if (it < ITER_-1)
        k_b<<<grid, blk, 0, stream>>>(x, r, r, pa, scal, it);
      else
        k_b_fin<<<grid, blk, 0, stream>>>(x, r, pa, ref, out, scal, it);
      pb = pa; pa = (pa == p0w) ? out : p0w;
    }
    /* parity: it=1..7 -> pa = ws1,out,ws1,out,ws1,out,ws1 ; fin reads ws1 */
  }
}

// Round 5
// 972.733 us; speedup vs baseline: 1.1582x; 1.1582x over previous
//
#include <hip/hip_runtime.h>

#define B_ 4
#define H_ 256
#define W_ 256
#define Z_ 64
#define NB_ (H_*W_*Z_)      /* 4194304 */
#define N_  (B_*NB_)        /* 16777216 */
#define ITER_ 8
#define EPS_ 1e-6f
#define SLOTS_ 64

/* scal layout (floats) */
#define RHO_OFF   0
#define ETA_OFF   ((ITER_+1)*B_*SLOTS_)
#define LOSS_OFF  (ETA_OFF + ITER_*B_*SLOTS_)
#define MAXE_OFF  (LOSS_OFF + SLOTS_)
#define SCAL_FLOATS (MAXE_OFF + SLOTS_)

struct F8 { float4 a, b; };

__device__ __forceinline__ float wsum(float v){
  v += __shfl_xor(v,32); v += __shfl_xor(v,16); v += __shfl_xor(v,8);
  v += __shfl_xor(v,4);  v += __shfl_xor(v,2);  v += __shfl_xor(v,1);
  return v;
}
__device__ __forceinline__ float wmaxr(float v){
  v = fmaxf(v,__shfl_xor(v,32)); v = fmaxf(v,__shfl_xor(v,16));
  v = fmaxf(v,__shfl_xor(v,8));  v = fmaxf(v,__shfl_xor(v,4));
  v = fmaxf(v,__shfl_xor(v,2));  v = fmaxf(v,__shfl_xor(v,1));
  return v;
}
__device__ __forceinline__ float read_sum(const float* s){
  return wsum(s[threadIdx.x & 63]);
}
__device__ __forceinline__ void block_atomic_sum(float v, float* dst, float* lds){
  v = wsum(v);
  int wid = threadIdx.x >> 6, lane = threadIdx.x & 63;
  if (lane == 0) lds[wid] = v;
  __syncthreads();
  if (threadIdx.x == 0) atomicAdd(dst, lds[0]+lds[1]+lds[2]+lds[3]);
}

__device__ __forceinline__ float4 ld4(const float* p){ return *(const float4*)p; }

__device__ __forceinline__ void sub8(F8& s, const F8& n){
  s.a.x-=n.a.x; s.a.y-=n.a.y; s.a.z-=n.a.z; s.a.w-=n.a.w;
  s.b.x-=n.b.x; s.b.y-=n.b.y; s.b.z-=n.b.z; s.b.w-=n.b.w;
}

/* z-part of stencil: zl/zr via wave shuffle (neighbor lane's center values).
   lane L has zc = L&7; zc>0 -> zl = lane L-1's c.b.w; zc<7 -> zr = lane L+1's c.a.x */
__device__ __forceinline__ void zcore(const F8& c, int zc, F8& st){
  float zl = __shfl_up(c.b.w, 1);
  float zr = __shfl_down(c.a.x, 1);
  zl = (zc > 0) ? zl : 0.f;
  zr = (zc < 7) ? zr : 0.f;
  st.a.x = 6.f*c.a.x - zl    - c.a.y;
  st.a.y = 6.f*c.a.y - c.a.x - c.a.z;
  st.a.z = 6.f*c.a.z - c.a.y - c.a.w;
  st.a.w = 6.f*c.a.w - c.a.z - c.b.x;
  st.b.x = 6.f*c.b.x - c.a.w - c.b.y;
  st.b.y = 6.f*c.b.y - c.b.x - c.b.z;
  st.b.z = 6.f*c.b.z - c.b.y - c.b.w;
  st.b.w = 6.f*c.b.w - c.b.z - zr;
}

/* ---- 2-row stencils: rows h0, h0+1; cross-row h-neighbors reuse registers ---- */
__device__ __forceinline__ void stencil1_2(const float* __restrict__ a, int base0,
                                           int w, int h0, int zc,
                                           F8& c0, F8& c1, F8& st0, F8& st1)
{
  const int base1 = base0 + W_*Z_;
  c0.a = ld4(a+base0); c0.b = ld4(a+base0+4);
  c1.a = ld4(a+base1); c1.b = ld4(a+base1+4);
  zcore(c0, zc, st0);
  zcore(c1, zc, st1);
  F8 t;
  if (w > 0)    { t.a = ld4(a+base0-Z_); t.b = ld4(a+base0-Z_+4); sub8(st0,t);
                  t.a = ld4(a+base1-Z_); t.b = ld4(a+base1-Z_+4); sub8(st1,t); }
  if (w < W_-1) { t.a = ld4(a+base0+Z_); t.b = ld4(a+base0+Z_+4); sub8(st0,t);
                  t.a = ld4(a+base1+Z_); t.b = ld4(a+base1+Z_+4); sub8(st1,t); }
  if (h0 > 0)   { t.a = ld4(a+base0-W_*Z_); t.b = ld4(a+base0-W_*Z_+4); sub8(st0,t); }
  sub8(st0, c1);   /* h+1 of row0 = center of row1 */
  sub8(st1, c0);   /* h-1 of row1 = center of row0 */
  if (h0 < H_-2){ t.a = ld4(a+base1+W_*Z_); t.b = ld4(a+base1+W_*Z_+4); sub8(st1,t); }
}

__device__ __forceinline__ F8 comb8(const float* r, const float* p, float beta, int idx){
  F8 o;
  float4 ra = ld4(r+idx), rb = ld4(r+idx+4);
  float4 pa = ld4(p+idx), pb = ld4(p+idx+4);
  o.a.x = ra.x + beta*pa.x; o.a.y = ra.y + beta*pa.y;
  o.a.z = ra.z + beta*pa.z; o.a.w = ra.w + beta*pa.w;
  o.b.x = rb.x + beta*pb.x; o.b.y = rb.y + beta*pb.y;
  o.b.z = rb.z + beta*pb.z; o.b.w = rb.w + beta*pb.w;
  return o;
}
__device__ __forceinline__ void stencil2_2(const float* __restrict__ r,
                                           const float* __restrict__ p, float beta,
                                           int base0, int w, int h0, int zc,
                                           F8& c0, F8& c1, F8& st0, F8& st1)
{
  const int base1 = base0 + W_*Z_;
  c0 = comb8(r,p,beta,base0);
  c1 = comb8(r,p,beta,base1);
  zcore(c0, zc, st0);
  zcore(c1, zc, st1);
  if (w > 0)    { sub8(st0, comb8(r,p,beta,base0-Z_));
                  sub8(st1, comb8(r,p,beta,base1-Z_)); }
  if (w < W_-1) { sub8(st0, comb8(r,p,beta,base0+Z_));
                  sub8(st1, comb8(r,p,beta,base1+Z_)); }
  if (h0 > 0)   sub8(st0, comb8(r,p,beta,base0-W_*Z_));
  sub8(st0, c1);
  sub8(st1, c0);
  if (h0 < H_-2) sub8(st1, comb8(r,p,beta,base1+W_*Z_));
}

__device__ __forceinline__ float dot8(const F8& a, const F8& b){
  return a.a.x*b.a.x + a.a.y*b.a.y + a.a.z*b.a.z + a.a.w*b.a.w
       + a.b.x*b.b.x + a.b.y*b.b.y + a.b.z*b.b.z + a.b.w*b.b.w;
}

#define IDX2_SETUP \
  const int zc = threadIdx.x & 7; \
  const int wl = threadIdx.x >> 3; \
  const int w  = blockIdx.x*32 + wl; \
  const int h0 = blockIdx.y*2; \
  const int bb = blockIdx.z; \
  const int base0 = ((bb*H_ + h0)*W_ + w)*Z_ + zc*8; \
  const int flat = (blockIdx.z*gridDim.y + blockIdx.y)*gridDim.x + blockIdx.x; \
  const int slot = flat & (SLOTS_-1);

/* r = b - A x ; rho0 = <r,r> per batch (2 rows/thread) */
__global__ __launch_bounds__(256) void k_init2(const float* __restrict__ x,
                                               const float* __restrict__ b,
                                               float* __restrict__ r,
                                               float* scal)
{
  __shared__ float lds[4];
  IDX2_SETUP
  const int base1 = base0 + W_*Z_;
  F8 c0,c1,st0,st1;
  stencil1_2(x, base0, w, h0, zc, c0, c1, st0, st1);
  float4 b0 = ld4(b+base0), b1 = ld4(b+base0+4);
  float4 b2 = ld4(b+base1), b3 = ld4(b+base1+4);
  F8 rv0, rv1;
  rv0.a = make_float4(b0.x-st0.a.x, b0.y-st0.a.y, b0.z-st0.a.z, b0.w-st0.a.w);
  rv0.b = make_float4(b1.x-st0.b.x, b1.y-st0.b.y, b1.z-st0.b.z, b1.w-st0.b.w);
  rv1.a = make_float4(b2.x-st1.a.x, b2.y-st1.a.y, b2.z-st1.a.z, b2.w-st1.a.w);
  rv1.b = make_float4(b3.x-st1.b.x, b3.y-st1.b.y, b3.z-st1.b.z, b3.w-st1.b.w);
  *(float4*)(r+base0)   = rv0.a;
  *(float4*)(r+base0+4) = rv0.b;
  *(float4*)(r+base1)   = rv1.a;
  *(float4*)(r+base1+4) = rv1.b;
  block_atomic_sum(dot8(rv0,rv0)+dot8(rv1,rv1),
                   scal + RHO_OFF + (0*B_+bb)*SLOTS_ + slot, lds);
}

/* it==0: eta0 = <r, A r>; optional p0 = r copy (fallback path only) */
__global__ __launch_bounds__(256) void k_a0_2(const float* __restrict__ r,
                                              float* __restrict__ pnew,
                                              float* scal)
{
  __shared__ float lds[4];
  IDX2_SETUP
  const int base1 = base0 + W_*Z_;
  F8 c0,c1,st0,st1;
  stencil1_2(r, base0, w, h0, zc, c0, c1, st0, st1);
  if (pnew) {
    *(float4*)(pnew+base0)   = c0.a; *(float4*)(pnew+base0+4) = c0.b;
    *(float4*)(pnew+base1)   = c1.a; *(float4*)(pnew+base1+4) = c1.b;
  }
  block_atomic_sum(dot8(c0,st0)+dot8(c1,st1),
                   scal + ETA_OFF + (0*B_+bb)*SLOTS_ + slot, lds);
}

/* it>=1: p_new = r + beta*p_old ; eta = <p_new, A p_new> (2 rows/thread) */
__global__ __launch_bounds__(256) void k_a2(const float* __restrict__ r,
                                            const float* __restrict__ pold,
                                            float* __restrict__ pnew,
                                            float* scal, int it)
{
  __shared__ float lds[4];
  IDX2_SETUP
  const int base1 = base0 + W_*Z_;
  float num = read_sum(scal + RHO_OFF + (it*B_+bb)*SLOTS_);
  float den = read_sum(scal + RHO_OFF + ((it-1)*B_+bb)*SLOTS_);
  float beta = num / (den + EPS_);
  F8 c0,c1,st0,st1;
  stencil2_2(r, pold, beta, base0, w, h0, zc, c0, c1, st0, st1);
  *(float4*)(pnew+base0)   = c0.a;
  *(float4*)(pnew+base0+4) = c0.b;
  *(float4*)(pnew+base1)   = c1.a;
  *(float4*)(pnew+base1+4) = c1.b;
  block_atomic_sum(dot8(c0,st0)+dot8(c1,st1),
                   scal + ETA_OFF + (it*B_+bb)*SLOTS_ + slot, lds);
}

/* it<7: alpha; x += alpha p; r_out = r_in - alpha*A p; rho_next (2 rows/thread).
   r_in may alias p (it==0) and r_out may alias r_in (in-place). */
__global__ __launch_bounds__(256) void k_b2(float* __restrict__ x,
                                            const float* r_in,
                                            float* r_out,
                                            const float* p,
                                            float* scal, int it)
{
  __shared__ float lds[4];
  IDX2_SETUP
  const int base1 = base0 + W_*Z_;
  float num = read_sum(scal + RHO_OFF + (it*B_+bb)*SLOTS_);
  float den = read_sum(scal + ETA_OFF + (it*B_+bb)*SLOTS_);
  float alpha = num / (den + EPS_);
  F8 c0,c1,st0,st1;
  stencil1_2(p, base0, w, h0, zc, c0, c1, st0, st1);
  float rho = 0.f;
  {
    float4 x0 = ld4(x+base0), x1 = ld4(x+base0+4);
    x0.x += alpha*c0.a.x; x0.y += alpha*c0.a.y; x0.z += alpha*c0.a.z; x0.w += alpha*c0.a.w;
    x1.x += alpha*c0.b.x; x1.y += alpha*c0.b.y; x1.z += alpha*c0.b.z; x1.w += alpha*c0.b.w;
    *(float4*)(x+base0)   = x0;
    *(float4*)(x+base0+4) = x1;
    float4 r0 = ld4(r_in+base0), r1 = ld4(r_in+base0+4);
    r0.x -= alpha*st0.a.x; r0.y -= alpha*st0.a.y; r0.z -= alpha*st0.a.z; r0.w -= alpha*st0.a.w;
    r1.x -= alpha*st0.b.x; r1.y -= alpha*st0.b.y; r1.z -= alpha*st0.b.z; r1.w -= alpha*st0.b.w;
    *(float4*)(r_out+base0)   = r0;
    *(float4*)(r_out+base0+4) = r1;
    rho += r0.x*r0.x + r0.y*r0.y + r0.z*r0.z + r0.w*r0.w
         + r1.x*r1.x + r1.y*r1.y + r1.z*r1.z + r1.w*r1.w;
  }
  {
    float4 x0 = ld4(x+base1), x1 = ld4(x+base1+4);
    x0.x += alpha*c1.a.x; x0.y += alpha*c1.a.y; x0.z += alpha*c1.a.z; x0.w += alpha*c1.a.w;
    x1.x += alpha*c1.b.x; x1.y += alpha*c1.b.y; x1.z += alpha*c1.b.z; x1.w += alpha*c1.b.w;
    *(float4*)(x+base1)   = x0;
    *(float4*)(x+base1+4) = x1;
    float4 r0 = ld4(r_in+base1), r1 = ld4(r_in+base1+4);
    r0.x -= alpha*st1.a.x; r0.y -= alpha*st1.a.y; r0.z -= alpha*st1.a.z; r0.w -= alpha*st1.a.w;
    r1.x -= alpha*st1.b.x; r1.y -= alpha*st1.b.y; r1.z -= alpha*st1.b.z; r1.w -= alpha*st1.b.w;
    *(float4*)(r_out+base1)   = r0;
    *(float4*)(r_out+base1+4) = r1;
    rho += r0.x*r0.x + r0.y*r0.y + r0.z*r0.z + r0.w*r0.w
         + r1.x*r1.x + r1.y*r1.y + r1.z*r1.z + r1.w*r1.w;
  }
  block_atomic_sum(rho, scal + RHO_OFF + ((it+1)*B_+bb)*SLOTS_ + slot, lds);
}

/* ==== round-0-verbatim final kernel + scalar fold (known 72 us) ==== */
__device__ __forceinline__ void sten_core_o(const F8& c, const F8& wm, const F8& wp,
                                            const F8& hm, const F8& hp,
                                            float zl, float zr, F8& st)
{
  st.a.x = 6.f*c.a.x - wm.a.x - wp.a.x - hm.a.x - hp.a.x - zl     - c.a.y;
  st.a.y = 6.f*c.a.y - wm.a.y - wp.a.y - hm.a.y - hp.a.y - c.a.x  - c.a.z;
  st.a.z = 6.f*c.a.z - wm.a.z - wp.a.z - hm.a.z - hp.a.z - c.a.y  - c.a.w;
  st.a.w = 6.f*c.a.w - wm.a.w - wp.a.w - hm.a.w - hp.a.w - c.a.z  - c.b.x;
  st.b.x = 6.f*c.b.x - wm.b.x - wp.b.x - hm.b.x - hp.b.x - c.a.w  - c.b.y;
  st.b.y = 6.f*c.b.y - wm.b.y - wp.b.y - hm.b.y - hp.b.y - c.b.x  - c.b.z;
  st.b.z = 6.f*c.b.z - wm.b.z - wp.b.z - hm.b.z - hp.b.z - c.b.y  - c.b.w;
  st.b.w = 6.f*c.b.w - wm.b.w - wp.b.w - hm.b.w - hp.b.w - c.b.z  - zr;
}
__device__ __forceinline__ void stencil1_o(const float* __restrict__ a, int base,
                                           int w, int h, int zc, F8& c, F8& st)
{
  c.a = ld4(a+base); c.b = ld4(a+base+4);
  F8 zero; zero.a = make_float4(0,0,0,0); zero.b = zero.a;
  F8 wm = zero, wp = zero, hm = zero, hp = zero;
  if (w > 0)    { wm.a = ld4(a+base-Z_);    wm.b = ld4(a+base-Z_+4); }
  if (w < W_-1) { wp.a = ld4(a+base+Z_);    wp.b = ld4(a+base+Z_+4); }
  if (h > 0)    { hm.a = ld4(a+base-W_*Z_); hm.b = ld4(a+base-W_*Z_+4); }
  if (h < H_-1) { hp.a = ld4(a+base+W_*Z_); hp.b = ld4(a+base+W_*Z_+4); }
  float zl = (zc > 0) ? a[base-1] : 0.f;
  float zr = (zc < 7) ? a[base+8] : 0.f;
  sten_core_o(c, wm, wp, hm, hp, zl, zr, st);
}

__global__ __launch_bounds__(256) void k_b_fin(const float* __restrict__ x,
                                               const float* __restrict__ r,
                                               const float* __restrict__ p,
                                               const float* __restrict__ ref,
                                               float* __restrict__ out,
                                               float* scal, int it)
{
  __shared__ float xs[2048];
  __shared__ float lds[12];
  const int zc = threadIdx.x & 7;
  const int wl = threadIdx.x >> 3;
  const int w  = blockIdx.x*32 + wl;
  const int h  = blockIdx.y;
  const int bb = blockIdx.z;
  const int base = ((bb*H_ + h)*W_ + w)*Z_ + zc*8;
  const int flat = (blockIdx.z*gridDim.y + blockIdx.y)*gridDim.x + blockIdx.x;
  const int slot = flat & (SLOTS_-1);
  float num = read_sum(scal + RHO_OFF + (it*B_+bb)*SLOTS_);
  float den = read_sum(scal + ETA_OFF + (it*B_+bb)*SLOTS_);
  float alpha = num / (den + EPS_);
  F8 c, st;
  stencil1_o(p, base, w, h, zc, c, st);
  float4 x0 = ld4(x+base), x1 = ld4(x+base+4);
  x0.x += alpha*c.a.x; x0.y += alpha*c.a.y; x0.z += alpha*c.a.z; x0.w += alpha*c.a.w;
  x1.x += alpha*c.b.x; x1.y += alpha*c.b.y; x1.z += alpha*c.b.z; x1.w += alpha*c.b.w;
  float4 r0 = ld4(r+base), r1 = ld4(r+base+4);
  r0.x -= alpha*st.a.x; r0.y -= alpha*st.a.y; r0.z -= alpha*st.a.z; r0.w -= alpha*st.a.w;
  r1.x -= alpha*st.b.x; r1.y -= alpha*st.b.y; r1.z -= alpha*st.b.z; r1.w -= alpha*st.b.w;
  float rho = r0.x*r0.x + r0.y*r0.y + r0.z*r0.z + r0.w*r0.w
            + r1.x*r1.x + r1.y*r1.y + r1.z*r1.z + r1.w*r1.w;

  const int t = threadIdx.x;
  xs[t*8+0] = x0.x; xs[t*8+1] = x0.y; xs[t*8+2] = x0.z; xs[t*8+3] = x0.w;
  xs[t*8+4] = x1.x; xs[t*8+5] = x1.y; xs[t*8+6] = x1.z; xs[t*8+7] = x1.w;

  float4 f0 = ld4(ref+base), f1 = ld4(ref+base+4);
  float d0 = x0.x-f0.x, d1 = x0.y-f0.y, d2 = x0.z-f0.z, d3 = x0.w-f0.w;
  float d4 = x1.x-f1.x, d5 = x1.y-f1.y, d6 = x1.z-f1.z, d7 = x1.w-f1.w;
  float loss = d0*d0+d1*d1+d2*d2+d3*d3+d4*d4+d5*d5+d6*d6+d7*d7;
  float me = fmaxf(fmaxf(fmaxf(fabsf(d0),fabsf(d1)),fmaxf(fabsf(d2),fabsf(d3))),
                   fmaxf(fmaxf(fabsf(d4),fabsf(d5)),fmaxf(fabsf(d6),fabsf(d7))));

  float rs = wsum(rho), ls = wsum(loss), ms = wmaxr(me);
  int wid = t >> 6, lane = t & 63;
  if (lane == 0) { lds[wid] = rs; lds[4+wid] = ls; lds[8+wid] = ms; }
  __syncthreads();
  if (t == 0) {
    atomicAdd(scal + RHO_OFF + ((it+1)*B_+bb)*SLOTS_ + slot, lds[0]+lds[1]+lds[2]+lds[3]);
    atomicAdd(scal + LOSS_OFF + slot, lds[4]+lds[5]+lds[6]+lds[7]);
    float bm = fmaxf(fmaxf(lds[8],lds[9]), fmaxf(lds[10],lds[11]));
    atomicMax((unsigned int*)(scal + MAXE_OFF) + slot, __float_as_uint(bm));
  }

  const int S = flat * 2048;
  #pragma unroll
  for (int c2 = 0; c2 < 2; ++c2) {
    int q = t + 256*c2;
    if (q < 511) {
      float4 v = make_float4(xs[3+4*q], xs[4+4*q], xs[5+4*q], xs[6+4*q]);
      *(float4*)(out + S + 4 + 4*q) = v;
    } else if (q == 511) {
      out[S+1] = xs[0]; out[S+2] = xs[1]; out[S+3] = xs[2];
      out[S+2048] = xs[2047];
    }
  }
}

__global__ __launch_bounds__(64) void k_scal(const float* scal, float* out)
{
  int lane = threadIdx.x;
  float loss = wsum(scal[LOSS_OFF + lane]);
  float me   = wmaxr(__uint_as_float(((const unsigned int*)scal)[MAXE_OFF + lane]));
  float rho_sum = 0.f;
  for (int bb = 0; bb < B_; ++bb)
    rho_sum += wsum(scal[RHO_OFF + (ITER_*B_+bb)*SLOTS_ + lane]);
  if (lane == 0) {
    out[0]      = loss / (float)N_;
    out[1+N_]   = me;
    out[2+N_]   = rho_sum / (float)B_;
  }
}

extern "C" void kernel_launch(void* const* d_in, const int* in_sizes, int n_in,
                              void* d_out, int out_size, void* d_ws, size_t ws_size,
                              hipStream_t stream) {
  float* x         = (float*)d_in[0];
  const float* bv  = (const float*)d_in[1];
  const float* ref = (const float*)d_in[2];
  float* out       = (float*)d_out;
  float* ws        = (float*)d_ws;

  dim3 g2(W_/32, H_/2, B_), gF(W_/32, H_, B_), blk(256);
  bool fast = ws_size >= ((size_t)3*N_ + SCAL_FLOATS) * sizeof(float);

  if (fast) {
    /* R0 = r0 (== p0), R1 = live r, P0/P1 = p ping-pong (P1 = out scratch) */
    float* R0 = ws;
    float* R1 = ws + N_;
    float* P0 = ws + 2*(size_t)N_;
    float* P1 = out;
    float* scal = ws + 3*(size_t)N_;
    (void)hipMemsetAsync(scal, 0, SCAL_FLOATS*sizeof(float), stream);

    k_init2<<<g2, blk, 0, stream>>>(x, bv, R0, scal);
    k_a0_2 <<<g2, blk, 0, stream>>>(R0, nullptr, scal);           /* p0 == r0 */
    k_b2   <<<g2, blk, 0, stream>>>(x, R0, R1, R0, scal, 0);      /* r1 -> R1 */
    float* pa = P0; float* pb = R0;
    for (int it = 1; it < ITER_; ++it) {
      k_a2<<<g2, blk, 0, stream>>>(R1, pb, pa, scal, it);
      if (it < ITER_-1)
        k_b2<<<g2, blk, 0, stream>>>(x, R1, R1, pa, scal, it);    /* in-place r */
      else
        k_b_fin<<<gF, blk, 0, stream>>>(x, R1, pa, ref, out, scal, it);
      pb = pa; pa = (pa == P0) ? P1 : P0;
    }
    /* parity: it=1..7 -> pa = P0,P1,P0,P1,P0,P1,P0 ; fin reads P0 (ws, not out) */
  } else {
    /* fallback: r in-place in ws0; p ping-pong ws1/out; it0 copies p0 to out */
    float* r    = ws;
    float* p0w  = ws + N_;
    float* scal = ws + 2*(size_t)N_;
    (void)hipMemsetAsync(scal, 0, SCAL_FLOATS*sizeof(float), stream);

    k_init2<<<g2, blk, 0, stream>>>(x, bv, r, scal);
    k_a0_2 <<<g2, blk, 0, stream>>>(r, out, scal);                /* p0 -> out */
    k_b2   <<<g2, blk, 0, stream>>>(x, r, r, out, scal, 0);
    float* pa = p0w; float* pb = out;
    for (int it = 1; it < ITER_; ++it) {
      k_a2<<<g2, blk, 0, stream>>>(r, pb, pa, scal, it);
      if (it < ITER_-1)
        k_b2<<<g2, blk, 0, stream>>>(x, r, r, pa, scal, it);
      else
        k_b_fin<<<gF, blk, 0, stream>>>(x, r, pa, ref, out, scal, it);
      pb = pa; pa = (pa == p0w) ? out : p0w;
    }
    /* parity: it=1..7 -> pa = ws1,out,ws1,out,ws1,out,ws1 ; fin reads ws1 */
  }
  k_scal<<<1, 64, 0, stream>>>((fast ? ws + 3*(size_t)N_ : ws + 2*(size_t)N_), out);
}

// Round 6
// 943.099 us; speedup vs baseline: 1.1946x; 1.0314x over previous
//
#include <hip/hip_runtime.h>

#define B_ 4
#define H_ 256
#define W_ 256
#define Z_ 64
#define NB_ (H_*W_*Z_)      /* 4194304 */
#define N_  (B_*NB_)        /* 16777216 */
#define ITER_ 8
#define EPS_ 1e-6f
#define SLOTS_ 64

/* scal layout (floats) */
#define RHO_OFF   0
#define ETA_OFF   ((ITER_+1)*B_*SLOTS_)
#define LOSS_OFF  (ETA_OFF + ITER_*B_*SLOTS_)
#define MAXE_OFF  (LOSS_OFF + SLOTS_)
#define SCAL_FLOATS (MAXE_OFF + SLOTS_)

struct F8 { float4 a, b; };

__device__ __forceinline__ float wsum(float v){
  v += __shfl_xor(v,32); v += __shfl_xor(v,16); v += __shfl_xor(v,8);
  v += __shfl_xor(v,4);  v += __shfl_xor(v,2);  v += __shfl_xor(v,1);
  return v;
}
__device__ __forceinline__ float wmaxr(float v){
  v = fmaxf(v,__shfl_xor(v,32)); v = fmaxf(v,__shfl_xor(v,16));
  v = fmaxf(v,__shfl_xor(v,8));  v = fmaxf(v,__shfl_xor(v,4));
  v = fmaxf(v,__shfl_xor(v,2));  v = fmaxf(v,__shfl_xor(v,1));
  return v;
}
__device__ __forceinline__ float read_sum(const float* s){
  return wsum(s[threadIdx.x & 63]);
}
__device__ __forceinline__ void block_atomic_sum(float v, float* dst, float* lds){
  v = wsum(v);
  int wid = threadIdx.x >> 6, lane = threadIdx.x & 63;
  if (lane == 0) lds[wid] = v;
  __syncthreads();
  if (threadIdx.x == 0) atomicAdd(dst, lds[0]+lds[1]+lds[2]+lds[3]);
}

__device__ __forceinline__ float4 ld4(const float* p){ return *(const float4*)p; }

__device__ __forceinline__ void sub8(F8& s, const F8& n){
  s.a.x-=n.a.x; s.a.y-=n.a.y; s.a.z-=n.a.z; s.a.w-=n.a.w;
  s.b.x-=n.b.x; s.b.y-=n.b.y; s.b.z-=n.b.z; s.b.w-=n.b.w;
}

/* z-part of stencil: zl/zr via wave shuffle (neighbor lane's center values). */
__device__ __forceinline__ void zcore(const F8& c, int zc, F8& st){
  float zl = __shfl_up(c.b.w, 1);
  float zr = __shfl_down(c.a.x, 1);
  zl = (zc > 0) ? zl : 0.f;
  zr = (zc < 7) ? zr : 0.f;
  st.a.x = 6.f*c.a.x - zl    - c.a.y;
  st.a.y = 6.f*c.a.y - c.a.x - c.a.z;
  st.a.z = 6.f*c.a.z - c.a.y - c.a.w;
  st.a.w = 6.f*c.a.w - c.a.z - c.b.x;
  st.b.x = 6.f*c.b.x - c.a.w - c.b.y;
  st.b.y = 6.f*c.b.y - c.b.x - c.b.z;
  st.b.z = 6.f*c.b.z - c.b.y - c.b.w;
  st.b.w = 6.f*c.b.w - c.b.z - zr;
}

/* ---- 2-row stencils: rows h0, h0+1; cross-row h-neighbors reuse registers ---- */
__device__ __forceinline__ void stencil1_2(const float* __restrict__ a, int base0,
                                           int w, int h0, int zc,
                                           F8& c0, F8& c1, F8& st0, F8& st1)
{
  const int base1 = base0 + W_*Z_;
  c0.a = ld4(a+base0); c0.b = ld4(a+base0+4);
  c1.a = ld4(a+base1); c1.b = ld4(a+base1+4);
  zcore(c0, zc, st0);
  zcore(c1, zc, st1);
  F8 t;
  if (w > 0)    { t.a = ld4(a+base0-Z_); t.b = ld4(a+base0-Z_+4); sub8(st0,t);
                  t.a = ld4(a+base1-Z_); t.b = ld4(a+base1-Z_+4); sub8(st1,t); }
  if (w < W_-1) { t.a = ld4(a+base0+Z_); t.b = ld4(a+base0+Z_+4); sub8(st0,t);
                  t.a = ld4(a+base1+Z_); t.b = ld4(a+base1+Z_+4); sub8(st1,t); }
  if (h0 > 0)   { t.a = ld4(a+base0-W_*Z_); t.b = ld4(a+base0-W_*Z_+4); sub8(st0,t); }
  sub8(st0, c1);   /* h+1 of row0 = center of row1 */
  sub8(st1, c0);   /* h-1 of row1 = center of row0 */
  if (h0 < H_-2){ t.a = ld4(a+base1+W_*Z_); t.b = ld4(a+base1+W_*Z_+4); sub8(st1,t); }
}

__device__ __forceinline__ F8 comb8(const float* r, const float* p, float beta, int idx){
  F8 o;
  float4 ra = ld4(r+idx), rb = ld4(r+idx+4);
  float4 pa = ld4(p+idx), pb = ld4(p+idx+4);
  o.a.x = ra.x + beta*pa.x; o.a.y = ra.y + beta*pa.y;
  o.a.z = ra.z + beta*pa.z; o.a.w = ra.w + beta*pa.w;
  o.b.x = rb.x + beta*pb.x; o.b.y = rb.y + beta*pb.y;
  o.b.z = rb.z + beta*pb.z; o.b.w = rb.w + beta*pb.w;
  return o;
}
__device__ __forceinline__ void stencil2_2(const float* __restrict__ r,
                                           const float* __restrict__ p, float beta,
                                           int base0, int w, int h0, int zc,
                                           F8& c0, F8& c1, F8& st0, F8& st1)
{
  const int base1 = base0 + W_*Z_;
  c0 = comb8(r,p,beta,base0);
  c1 = comb8(r,p,beta,base1);
  zcore(c0, zc, st0);
  zcore(c1, zc, st1);
  if (w > 0)    { sub8(st0, comb8(r,p,beta,base0-Z_));
                  sub8(st1, comb8(r,p,beta,base1-Z_)); }
  if (w < W_-1) { sub8(st0, comb8(r,p,beta,base0+Z_));
                  sub8(st1, comb8(r,p,beta,base1+Z_)); }
  if (h0 > 0)   sub8(st0, comb8(r,p,beta,base0-W_*Z_));
  sub8(st0, c1);
  sub8(st1, c0);
  if (h0 < H_-2) sub8(st1, comb8(r,p,beta,base1+W_*Z_));
}

__device__ __forceinline__ float dot8(const F8& a, const F8& b){
  return a.a.x*b.a.x + a.a.y*b.a.y + a.a.z*b.a.z + a.a.w*b.a.w
       + a.b.x*b.b.x + a.b.y*b.b.y + a.b.z*b.b.z + a.b.w*b.b.w;
}

#define IDX2_SETUP \
  const int zc = threadIdx.x & 7; \
  const int wl = threadIdx.x >> 3; \
  const int w  = blockIdx.x*32 + wl; \
  const int h0 = blockIdx.y*2; \
  const int bb = blockIdx.z; \
  const int base0 = ((bb*H_ + h0)*W_ + w)*Z_ + zc*8; \
  const int flat = (blockIdx.z*gridDim.y + blockIdx.y)*gridDim.x + blockIdx.x; \
  const int slot = flat & (SLOTS_-1);

/* r = b - A x ; rho0 = <r,r> per batch (2 rows/thread) */
__global__ __launch_bounds__(256) void k_init2(const float* __restrict__ x,
                                               const float* __restrict__ b,
                                               float* __restrict__ r,
                                               float* scal)
{
  __shared__ float lds[4];
  IDX2_SETUP
  const int base1 = base0 + W_*Z_;
  F8 c0,c1,st0,st1;
  stencil1_2(x, base0, w, h0, zc, c0, c1, st0, st1);
  float4 b0 = ld4(b+base0), b1 = ld4(b+base0+4);
  float4 b2 = ld4(b+base1), b3 = ld4(b+base1+4);
  F8 rv0, rv1;
  rv0.a = make_float4(b0.x-st0.a.x, b0.y-st0.a.y, b0.z-st0.a.z, b0.w-st0.a.w);
  rv0.b = make_float4(b1.x-st0.b.x, b1.y-st0.b.y, b1.z-st0.b.z, b1.w-st0.b.w);
  rv1.a = make_float4(b2.x-st1.a.x, b2.y-st1.a.y, b2.z-st1.a.z, b2.w-st1.a.w);
  rv1.b = make_float4(b3.x-st1.b.x, b3.y-st1.b.y, b3.z-st1.b.z, b3.w-st1.b.w);
  *(float4*)(r+base0)   = rv0.a;
  *(float4*)(r+base0+4) = rv0.b;
  *(float4*)(r+base1)   = rv1.a;
  *(float4*)(r+base1+4) = rv1.b;
  block_atomic_sum(dot8(rv0,rv0)+dot8(rv1,rv1),
                   scal + RHO_OFF + (0*B_+bb)*SLOTS_ + slot, lds);
}

/* it==0: eta0 = <r, A r>; optional p0 = r copy (fallback path only) */
__global__ __launch_bounds__(256) void k_a0_2(const float* __restrict__ r,
                                              float* __restrict__ pnew,
                                              float* scal)
{
  __shared__ float lds[4];
  IDX2_SETUP
  const int base1 = base0 + W_*Z_;
  F8 c0,c1,st0,st1;
  stencil1_2(r, base0, w, h0, zc, c0, c1, st0, st1);
  if (pnew) {
    *(float4*)(pnew+base0)   = c0.a; *(float4*)(pnew+base0+4) = c0.b;
    *(float4*)(pnew+base1)   = c1.a; *(float4*)(pnew+base1+4) = c1.b;
  }
  block_atomic_sum(dot8(c0,st0)+dot8(c1,st1),
                   scal + ETA_OFF + (0*B_+bb)*SLOTS_ + slot, lds);
}

/* it>=1: p_new = r + beta*p_old ; eta = <p_new, A p_new> (2 rows/thread) */
__global__ __launch_bounds__(256) void k_a2(const float* __restrict__ r,
                                            const float* __restrict__ pold,
                                            float* __restrict__ pnew,
                                            float* scal, int it)
{
  __shared__ float lds[4];
  IDX2_SETUP
  const int base1 = base0 + W_*Z_;
  float num = read_sum(scal + RHO_OFF + (it*B_+bb)*SLOTS_);
  float den = read_sum(scal + RHO_OFF + ((it-1)*B_+bb)*SLOTS_);
  float beta = num / (den + EPS_);
  F8 c0,c1,st0,st1;
  stencil2_2(r, pold, beta, base0, w, h0, zc, c0, c1, st0, st1);
  *(float4*)(pnew+base0)   = c0.a;
  *(float4*)(pnew+base0+4) = c0.b;
  *(float4*)(pnew+base1)   = c1.a;
  *(float4*)(pnew+base1+4) = c1.b;
  block_atomic_sum(dot8(c0,st0)+dot8(c1,st1),
                   scal + ETA_OFF + (it*B_+bb)*SLOTS_ + slot, lds);
}

/* even it: NO x update (deferred); r_out = r_in - alpha*A p; rho_next */
__global__ __launch_bounds__(256) void k_b2_nox(const float* r_in,
                                                float* r_out,
                                                const float* p,
                                                float* scal, int it)
{
  __shared__ float lds[4];
  IDX2_SETUP
  const int base1 = base0 + W_*Z_;
  float num = read_sum(scal + RHO_OFF + (it*B_+bb)*SLOTS_);
  float den = read_sum(scal + ETA_OFF + (it*B_+bb)*SLOTS_);
  float alpha = num / (den + EPS_);
  F8 c0,c1,st0,st1;
  stencil1_2(p, base0, w, h0, zc, c0, c1, st0, st1);
  float rho = 0.f;
  {
    float4 r0 = ld4(r_in+base0), r1 = ld4(r_in+base0+4);
    r0.x -= alpha*st0.a.x; r0.y -= alpha*st0.a.y; r0.z -= alpha*st0.a.z; r0.w -= alpha*st0.a.w;
    r1.x -= alpha*st0.b.x; r1.y -= alpha*st0.b.y; r1.z -= alpha*st0.b.z; r1.w -= alpha*st0.b.w;
    *(float4*)(r_out+base0)   = r0;
    *(float4*)(r_out+base0+4) = r1;
    rho += r0.x*r0.x + r0.y*r0.y + r0.z*r0.z + r0.w*r0.w
         + r1.x*r1.x + r1.y*r1.y + r1.z*r1.z + r1.w*r1.w;
  }
  {
    float4 r0 = ld4(r_in+base1), r1 = ld4(r_in+base1+4);
    r0.x -= alpha*st1.a.x; r0.y -= alpha*st1.a.y; r0.z -= alpha*st1.a.z; r0.w -= alpha*st1.a.w;
    r1.x -= alpha*st1.b.x; r1.y -= alpha*st1.b.y; r1.z -= alpha*st1.b.z; r1.w -= alpha*st1.b.w;
    *(float4*)(r_out+base1)   = r0;
    *(float4*)(r_out+base1+4) = r1;
    rho += r0.x*r0.x + r0.y*r0.y + r0.z*r0.z + r0.w*r0.w
         + r1.x*r1.x + r1.y*r1.y + r1.z*r1.z + r1.w*r1.w;
  }
  block_atomic_sum(rho, scal + RHO_OFF + ((it+1)*B_+bb)*SLOTS_ + slot, lds);
}

/* odd it<7: x += alpha_prev*p_prev + alpha*p (two deferred terms);
   r_out = r_in - alpha*A p; rho_next */
__global__ __launch_bounds__(256) void k_b2_pair(float* __restrict__ x,
                                                 const float* r_in,
                                                 float* r_out,
                                                 const float* p,
                                                 const float* __restrict__ pprev,
                                                 float* scal, int it)
{
  __shared__ float lds[4];
  IDX2_SETUP
  const int base1 = base0 + W_*Z_;
  float num = read_sum(scal + RHO_OFF + (it*B_+bb)*SLOTS_);
  float den = read_sum(scal + ETA_OFF + (it*B_+bb)*SLOTS_);
  float alpha = num / (den + EPS_);
  float nump = read_sum(scal + RHO_OFF + ((it-1)*B_+bb)*SLOTS_);
  float denp = read_sum(scal + ETA_OFF + ((it-1)*B_+bb)*SLOTS_);
  float alphap = nump / (denp + EPS_);
  F8 c0,c1,st0,st1;
  stencil1_2(p, base0, w, h0, zc, c0, c1, st0, st1);
  float rho = 0.f;
  {
    float4 q0 = ld4(pprev+base0), q1 = ld4(pprev+base0+4);
    float4 x0 = ld4(x+base0), x1 = ld4(x+base0+4);
    x0.x += alphap*q0.x + alpha*c0.a.x; x0.y += alphap*q0.y + alpha*c0.a.y;
    x0.z += alphap*q0.z + alpha*c0.a.z; x0.w += alphap*q0.w + alpha*c0.a.w;
    x1.x += alphap*q1.x + alpha*c0.b.x; x1.y += alphap*q1.y + alpha*c0.b.y;
    x1.z += alphap*q1.z + alpha*c0.b.z; x1.w += alphap*q1.w + alpha*c0.b.w;
    *(float4*)(x+base0)   = x0;
    *(float4*)(x+base0+4) = x1;
    float4 r0 = ld4(r_in+base0), r1 = ld4(r_in+base0+4);
    r0.x -= alpha*st0.a.x; r0.y -= alpha*st0.a.y; r0.z -= alpha*st0.a.z; r0.w -= alpha*st0.a.w;
    r1.x -= alpha*st0.b.x; r1.y -= alpha*st0.b.y; r1.z -= alpha*st0.b.z; r1.w -= alpha*st0.b.w;
    *(float4*)(r_out+base0)   = r0;
    *(float4*)(r_out+base0+4) = r1;
    rho += r0.x*r0.x + r0.y*r0.y + r0.z*r0.z + r0.w*r0.w
         + r1.x*r1.x + r1.y*r1.y + r1.z*r1.z + r1.w*r1.w;
  }
  {
    float4 q0 = ld4(pprev+base1), q1 = ld4(pprev+base1+4);
    float4 x0 = ld4(x+base1), x1 = ld4(x+base1+4);
    x0.x += alphap*q0.x + alpha*c1.a.x; x0.y += alphap*q0.y + alpha*c1.a.y;
    x0.z += alphap*q0.z + alpha*c1.a.z; x0.w += alphap*q0.w + alpha*c1.a.w;
    x1.x += alphap*q1.x + alpha*c1.b.x; x1.y += alphap*q1.y + alpha*c1.b.y;
    x1.z += alphap*q1.z + alpha*c1.b.z; x1.w += alphap*q1.w + alpha*c1.b.w;
    *(float4*)(x+base1)   = x0;
    *(float4*)(x+base1+4) = x1;
    float4 r0 = ld4(r_in+base1), r1 = ld4(r_in+base1+4);
    r0.x -= alpha*st1.a.x; r0.y -= alpha*st1.a.y; r0.z -= alpha*st1.a.z; r0.w -= alpha*st1.a.w;
    r1.x -= alpha*st1.b.x; r1.y -= alpha*st1.b.y; r1.z -= alpha*st1.b.z; r1.w -= alpha*st1.b.w;
    *(float4*)(r_out+base1)   = r0;
    *(float4*)(r_out+base1+4) = r1;
    rho += r0.x*r0.x + r0.y*r0.y + r0.z*r0.z + r0.w*r0.w
         + r1.x*r1.x + r1.y*r1.y + r1.z*r1.z + r1.w*r1.w;
  }
  block_atomic_sum(rho, scal + RHO_OFF + ((it+1)*B_+bb)*SLOTS_ + slot, lds);
}

/* it==7: 2-row final; x_new = x + alphap*pprev + alpha*p (pprev may be null
   -> plain x + alpha*p); epilogue: loss/maxerr/rho8 + shifted out stores. */
__global__ __launch_bounds__(256) void k_fin2(const float* __restrict__ x,
                                              const float* __restrict__ r,
                                              const float* __restrict__ p,
                                              const float* pprev,
                                              const float* __restrict__ ref,
                                              float* __restrict__ out,
                                              float* scal, int it)
{
  __shared__ float xs[4096];
  __shared__ float lds[12];
  IDX2_SETUP
  const int base1 = base0 + W_*Z_;
  const int t = threadIdx.x;
  float num = read_sum(scal + RHO_OFF + (it*B_+bb)*SLOTS_);
  float den = read_sum(scal + ETA_OFF + (it*B_+bb)*SLOTS_);
  float alpha = num / (den + EPS_);
  float alphap = 0.f;
  if (pprev) {
    float nump = read_sum(scal + RHO_OFF + ((it-1)*B_+bb)*SLOTS_);
    float denp = read_sum(scal + ETA_OFF + ((it-1)*B_+bb)*SLOTS_);
    alphap = nump / (denp + EPS_);
  }
  F8 c0,c1,st0,st1;
  stencil1_2(p, base0, w, h0, zc, c0, c1, st0, st1);

  float rho = 0.f, loss = 0.f, me = 0.f;
  float4 xa0, xa1, xb0, xb1;
  {
    xa0 = ld4(x+base0); xa1 = ld4(x+base0+4);
    if (pprev) {
      float4 q0 = ld4(pprev+base0), q1 = ld4(pprev+base0+4);
      xa0.x += alphap*q0.x; xa0.y += alphap*q0.y; xa0.z += alphap*q0.z; xa0.w += alphap*q0.w;
      xa1.x += alphap*q1.x; xa1.y += alphap*q1.y; xa1.z += alphap*q1.z; xa1.w += alphap*q1.w;
    }
    xa0.x += alpha*c0.a.x; xa0.y += alpha*c0.a.y; xa0.z += alpha*c0.a.z; xa0.w += alpha*c0.a.w;
    xa1.x += alpha*c0.b.x; xa1.y += alpha*c0.b.y; xa1.z += alpha*c0.b.z; xa1.w += alpha*c0.b.w;
    float4 r0 = ld4(r+base0), r1 = ld4(r+base0+4);
    r0.x -= alpha*st0.a.x; r0.y -= alpha*st0.a.y; r0.z -= alpha*st0.a.z; r0.w -= alpha*st0.a.w;
    r1.x -= alpha*st0.b.x; r1.y -= alpha*st0.b.y; r1.z -= alpha*st0.b.z; r1.w -= alpha*st0.b.w;
    rho += r0.x*r0.x + r0.y*r0.y + r0.z*r0.z + r0.w*r0.w
         + r1.x*r1.x + r1.y*r1.y + r1.z*r1.z + r1.w*r1.w;
    float4 f0 = ld4(ref+base0), f1 = ld4(ref+base0+4);
    float d0 = xa0.x-f0.x, d1 = xa0.y-f0.y, d2 = xa0.z-f0.z, d3 = xa0.w-f0.w;
    float d4 = xa1.x-f1.x, d5 = xa1.y-f1.y, d6 = xa1.z-f1.z, d7 = xa1.w-f1.w;
    loss += d0*d0+d1*d1+d2*d2+d3*d3+d4*d4+d5*d5+d6*d6+d7*d7;
    me = fmaxf(me, fmaxf(fmaxf(fmaxf(fabsf(d0),fabsf(d1)),fmaxf(fabsf(d2),fabsf(d3))),
                         fmaxf(fmaxf(fabsf(d4),fabsf(d5)),fmaxf(fabsf(d6),fabsf(d7)))));
  }
  {
    xb0 = ld4(x+base1); xb1 = ld4(x+base1+4);
    if (pprev) {
      float4 q0 = ld4(pprev+base1), q1 = ld4(pprev+base1+4);
      xb0.x += alphap*q0.x; xb0.y += alphap*q0.y; xb0.z += alphap*q0.z; xb0.w += alphap*q0.w;
      xb1.x += alphap*q1.x; xb1.y += alphap*q1.y; xb1.z += alphap*q1.z; xb1.w += alphap*q1.w;
    }
    xb0.x += alpha*c1.a.x; xb0.y += alpha*c1.a.y; xb0.z += alpha*c1.a.z; xb0.w += alpha*c1.a.w;
    xb1.x += alpha*c1.b.x; xb1.y += alpha*c1.b.y; xb1.z += alpha*c1.b.z; xb1.w += alpha*c1.b.w;
    float4 r0 = ld4(r+base1), r1 = ld4(r+base1+4);
    r0.x -= alpha*st1.a.x; r0.y -= alpha*st1.a.y; r0.z -= alpha*st1.a.z; r0.w -= alpha*st1.a.w;
    r1.x -= alpha*st1.b.x; r1.y -= alpha*st1.b.y; r1.z -= alpha*st1.b.z; r1.w -= alpha*st1.b.w;
    rho += r0.x*r0.x + r0.y*r0.y + r0.z*r0.z + r0.w*r0.w
         + r1.x*r1.x + r1.y*r1.y + r1.z*r1.z + r1.w*r1.w;
    float4 f0 = ld4(ref+base1), f1 = ld4(ref+base1+4);
    float d0 = xb0.x-f0.x, d1 = xb0.y-f0.y, d2 = xb0.z-f0.z, d3 = xb0.w-f0.w;
    float d4 = xb1.x-f1.x, d5 = xb1.y-f1.y, d6 = xb1.z-f1.z, d7 = xb1.w-f1.w;
    loss += d0*d0+d1*d1+d2*d2+d3*d3+d4*d4+d5*d5+d6*d6+d7*d7;
    me = fmaxf(me, fmaxf(fmaxf(fmaxf(fabsf(d0),fabsf(d1)),fmaxf(fabsf(d2),fabsf(d3))),
                         fmaxf(fmaxf(fabsf(d4),fabsf(d5)),fmaxf(fabsf(d6),fabsf(d7)))));
  }

  /* stage both rows' x_new (stride-8, round-0 pattern) */
  xs[t*8+0] = xa0.x; xs[t*8+1] = xa0.y; xs[t*8+2] = xa0.z; xs[t*8+3] = xa0.w;
  xs[t*8+4] = xa1.x; xs[t*8+5] = xa1.y; xs[t*8+6] = xa1.z; xs[t*8+7] = xa1.w;
  xs[2048+t*8+0] = xb0.x; xs[2048+t*8+1] = xb0.y; xs[2048+t*8+2] = xb0.z; xs[2048+t*8+3] = xb0.w;
  xs[2048+t*8+4] = xb1.x; xs[2048+t*8+5] = xb1.y; xs[2048+t*8+6] = xb1.z; xs[2048+t*8+7] = xb1.w;

  float rs = wsum(rho), ls = wsum(loss), ms = wmaxr(me);
  int wid = t >> 6, lane = t & 63;
  if (lane == 0) { lds[wid] = rs; lds[4+wid] = ls; lds[8+wid] = ms; }
  __syncthreads();
  if (t == 0) {
    atomicAdd(scal + RHO_OFF + ((it+1)*B_+bb)*SLOTS_ + slot, lds[0]+lds[1]+lds[2]+lds[3]);
    atomicAdd(scal + LOSS_OFF + slot, lds[4]+lds[5]+lds[6]+lds[7]);
    float bm = fmaxf(fmaxf(lds[8],lds[9]), fmaxf(lds[10],lds[11]));
    atomicMax((unsigned int*)(scal + MAXE_OFF) + slot, __float_as_uint(bm));
  }

  /* per-row shifted aligned stores: row rr x-span [S, S+2048) -> out [S+1, S+2048] */
  const int S0 = ((bb*H_ + h0)*8 + (int)blockIdx.x)*2048;
  #pragma unroll
  for (int rr = 0; rr < 2; ++rr) {
    const float* xr = xs + rr*2048;
    const int S = S0 + rr*(8*2048);
    #pragma unroll
    for (int c2 = 0; c2 < 2; ++c2) {
      int q = t + 256*c2;
      if (q < 511) {
        float4 v = make_float4(xr[3+4*q], xr[4+4*q], xr[5+4*q], xr[6+4*q]);
        *(float4*)(out + S + 4 + 4*q) = v;
      } else if (q == 511) {
        out[S+1] = xr[0]; out[S+2] = xr[1]; out[S+3] = xr[2];
        out[S+2048] = xr[2047];
      }
    }
  }
}

/* fallback-path k_b (x updated every iteration) */
__global__ __launch_bounds__(256) void k_b2(float* __restrict__ x,
                                            const float* r_in,
                                            float* r_out,
                                            const float* p,
                                            float* scal, int it)
{
  __shared__ float lds[4];
  IDX2_SETUP
  const int base1 = base0 + W_*Z_;
  float num = read_sum(scal + RHO_OFF + (it*B_+bb)*SLOTS_);
  float den = read_sum(scal + ETA_OFF + (it*B_+bb)*SLOTS_);
  float alpha = num / (den + EPS_);
  F8 c0,c1,st0,st1;
  stencil1_2(p, base0, w, h0, zc, c0, c1, st0, st1);
  float rho = 0.f;
  {
    float4 x0 = ld4(x+base0), x1 = ld4(x+base0+4);
    x0.x += alpha*c0.a.x; x0.y += alpha*c0.a.y; x0.z += alpha*c0.a.z; x0.w += alpha*c0.a.w;
    x1.x += alpha*c0.b.x; x1.y += alpha*c0.b.y; x1.z += alpha*c0.b.z; x1.w += alpha*c0.b.w;
    *(float4*)(x+base0)   = x0;
    *(float4*)(x+base0+4) = x1;
    float4 r0 = ld4(r_in+base0), r1 = ld4(r_in+base0+4);
    r0.x -= alpha*st0.a.x; r0.y -= alpha*st0.a.y; r0.z -= alpha*st0.a.z; r0.w -= alpha*st0.a.w;
    r1.x -= alpha*st0.b.x; r1.y -= alpha*st0.b.y; r1.z -= alpha*st0.b.z; r1.w -= alpha*st0.b.w;
    *(float4*)(r_out+base0)   = r0;
    *(float4*)(r_out+base0+4) = r1;
    rho += r0.x*r0.x + r0.y*r0.y + r0.z*r0.z + r0.w*r0.w
         + r1.x*r1.x + r1.y*r1.y + r1.z*r1.z + r1.w*r1.w;
  }
  {
    float4 x0 = ld4(x+base1), x1 = ld4(x+base1+4);
    x0.x += alpha*c1.a.x; x0.y += alpha*c1.a.y; x0.z += alpha*c1.a.z; x0.w += alpha*c1.a.w;
    x1.x += alpha*c1.b.x; x1.y += alpha*c1.b.y; x1.z += alpha*c1.b.z; x1.w += alpha*c1.b.w;
    *(float4*)(x+base1)   = x0;
    *(float4*)(x+base1+4) = x1;
    float4 r0 = ld4(r_in+base1), r1 = ld4(r_in+base1+4);
    r0.x -= alpha*st1.a.x; r0.y -= alpha*st1.a.y; r0.z -= alpha*st1.a.z; r0.w -= alpha*st1.a.w;
    r1.x -= alpha*st1.b.x; r1.y -= alpha*st1.b.y; r1.z -= alpha*st1.b.z; r1.w -= alpha*st1.b.w;
    *(float4*)(r_out+base1)   = r0;
    *(float4*)(r_out+base1+4) = r1;
    rho += r0.x*r0.x + r0.y*r0.y + r0.z*r0.z + r0.w*r0.w
         + r1.x*r1.x + r1.y*r1.y + r1.z*r1.z + r1.w*r1.w;
  }
  block_atomic_sum(rho, scal + RHO_OFF + ((it+1)*B_+bb)*SLOTS_ + slot, lds);
}

__global__ __launch_bounds__(64) void k_scal(const float* scal, float* out)
{
  int lane = threadIdx.x;
  float loss = wsum(scal[LOSS_OFF + lane]);
  float me   = wmaxr(__uint_as_float(((const unsigned int*)scal)[MAXE_OFF + lane]));
  float rho_sum = 0.f;
  for (int bb = 0; bb < B_; ++bb)
    rho_sum += wsum(scal[RHO_OFF + (ITER_*B_+bb)*SLOTS_ + lane]);
  if (lane == 0) {
    out[0]      = loss / (float)N_;
    out[1+N_]   = me;
    out[2+N_]   = rho_sum / (float)B_;
  }
}

extern "C" void kernel_launch(void* const* d_in, const int* in_sizes, int n_in,
                              void* d_out, int out_size, void* d_ws, size_t ws_size,
                              hipStream_t stream) {
  float* x         = (float*)d_in[0];
  const float* bv  = (const float*)d_in[1];
  const float* ref = (const float*)d_in[2];
  float* out       = (float*)d_out;
  float* ws        = (float*)d_ws;

  dim3 g2(W_/32, H_/2, B_), blk(256);
  bool fast = ws_size >= ((size_t)3*N_ + SCAL_FLOATS) * sizeof(float);
  float* scal;

  if (fast) {
    /* R0: r0/p0, then even-generation p buffer. R1: live r. P0: odd-gen p.
       p-schedule: k_a2(it) writes pnew = odd(it)?P0:R0, reads the other.
       Deferred x: even its skip x; odd its add alpha_{it-1}*pprev + alpha_it*pcur. */
    float* R0 = ws;
    float* R1 = ws + N_;
    float* P0 = ws + 2*(size_t)N_;
    scal = ws + 3*(size_t)N_;
    (void)hipMemsetAsync(scal, 0, SCAL_FLOATS*sizeof(float), stream);

    k_init2 <<<g2, blk, 0, stream>>>(x, bv, R0, scal);
    k_a0_2  <<<g2, blk, 0, stream>>>(R0, nullptr, scal);       /* p0 == r0 == R0 */
    k_b2_nox<<<g2, blk, 0, stream>>>(R0, R1, R0, scal, 0);     /* r1 -> R1, no x */
    for (int it = 1; it < ITER_; ++it) {
      float* pnew = (it & 1) ? P0 : R0;
      float* pold = (it & 1) ? R0 : P0;
      k_a2<<<g2, blk, 0, stream>>>(R1, pold, pnew, scal, it);
      if (it == ITER_-1)        /* it=7: pnew=P0, pprev=R0 (holds p6) */
        k_fin2<<<g2, blk, 0, stream>>>(x, R1, pnew, pold, ref, out, scal, it);
      else if (it & 1)          /* odd: apply deferred pair alpha_{it-1},alpha_it */
        k_b2_pair<<<g2, blk, 0, stream>>>(x, R1, R1, pnew, pold, scal, it);
      else                      /* even: defer x */
        k_b2_nox<<<g2, blk, 0, stream>>>(R1, R1, pnew, scal, it);
    }
  } else {
    /* fallback: r in-place in ws0; p ping-pong ws1/out; x updated every iter;
       fin (it=7) reads ws1, pprev=null -> no out aliasing. */
    float* r    = ws;
    float* p0w  = ws + N_;
    scal = ws + 2*(size_t)N_;
    (void)hipMemsetAsync(scal, 0, SCAL_FLOATS*sizeof(float), stream);

    k_init2<<<g2, blk, 0, stream>>>(x, bv, r, scal);
    k_a0_2 <<<g2, blk, 0, stream>>>(r, out, scal);             /* p0 -> out */
    k_b2   <<<g2, blk, 0, stream>>>(x, r, r, out, scal, 0);
    float* pa = p0w; float* pb = out;
    for (int it = 1; it < ITER_; ++it) {
      k_a2<<<g2, blk, 0, stream>>>(r, pb, pa, scal, it);
      if (it < ITER_-1)
        k_b2<<<g2, blk, 0, stream>>>(x, r, r, pa, scal, it);
      else
        k_fin2<<<g2, blk, 0, stream>>>(x, r, pa, nullptr, ref, out, scal, it);
      pb = pa; pa = (pa == p0w) ? out : p0w;
    }
    /* parity: it=1..7 -> pa = ws1,out,ws1,out,ws1,out,ws1 ; fin reads ws1 */
  }
  k_scal<<<1, 64, 0, stream>>>(scal, out);
}